// Round 22
// baseline (71.464 us; speedup 1.0000x reference)
//
#include <hip/hip_runtime.h>

#define NB 2
#define NH 16
#define SEQ 4096
#define HD 64
#define DIM 1024
#define WIN 512

typedef float f32x16 __attribute__((ext_vector_type(16)));
typedef short bf16x8 __attribute__((ext_vector_type(8)));
typedef unsigned int u32x4 __attribute__((ext_vector_type(4)));
typedef unsigned int u32x2 __attribute__((ext_vector_type(2)));
typedef unsigned short u16;
typedef unsigned int u32;

__device__ __forceinline__ u16 f2bf(float x) {
    u32 u = __float_as_uint(x);
    u += 0x7FFFu + ((u >> 16) & 1u);
    return (u16)(u >> 16);
}

__device__ __forceinline__ u32 cvtpk(float lo, float hi) {
    u32 r;
    asm("v_cvt_pk_bf16_f32 %0, %1, %2" : "=v"(r) : "v"(lo), "v"(hi));
    return r;
}

// quadratic 2^x for |x| <= 0.19: rel err < 3.5e-4 (<< bf16 4e-3)
__device__ __forceinline__ float pexp2(float x) {
    return 1.f + x * (0.69314718f + x * 0.24022651f);
}

// ---------------- k: l2-normalize + rope -> bf16, head-major (local trig arrays) ----------------
__device__ __forceinline__ void norm_rope_row2(const float* __restrict__ row,
                                               const float (&cr)[8], const float (&sr)[8],
                                               float scale, u16* __restrict__ dst, int a) {
    float4 u0 = *(const float4*)(row + 8 * a);
    float4 u1 = *(const float4*)(row + 8 * a + 4);
    float4 v0 = *(const float4*)(row + 32 + 8 * a);
    float4 v1 = *(const float4*)(row + 32 + 8 * a + 4);
    float x1[8] = {u0.x, u0.y, u0.z, u0.w, u1.x, u1.y, u1.z, u1.w};
    float x2[8] = {v0.x, v0.y, v0.z, v0.w, v1.x, v1.y, v1.z, v1.w};
    float ss = 0.f;
#pragma unroll
    for (int i = 0; i < 8; ++i) ss += x1[i] * x1[i] + x2[i] * x2[i];
    ss += __shfl_xor(ss, 1);
    ss += __shfl_xor(ss, 2);
    float rn = scale / fmaxf(sqrtf(ss), 1e-6f);
    u16 o1[8], o2[8];
#pragma unroll
    for (int i = 0; i < 8; ++i) {
        float c = cr[i], sn = sr[i];
        o1[i] = f2bf((x1[i] * c + x2[i] * sn) * rn);
        o2[i] = f2bf((x2[i] * c - x1[i] * sn) * rn);
    }
    uint4 w1, w2;
    w1.x = (u32)o1[0] | ((u32)o1[1] << 16); w1.y = (u32)o1[2] | ((u32)o1[3] << 16);
    w1.z = (u32)o1[4] | ((u32)o1[5] << 16); w1.w = (u32)o1[6] | ((u32)o1[7] << 16);
    w2.x = (u32)o2[0] | ((u32)o2[1] << 16); w2.y = (u32)o2[2] | ((u32)o2[3] << 16);
    w2.z = (u32)o2[4] | ((u32)o2[5] << 16); w2.w = (u32)o2[6] | ((u32)o2[7] << 16);
    *(uint4*)(dst + 8 * a) = w1;
    *(uint4*)(dst + 32 + 8 * a) = w2;
}

// ---------------- merged prep: K-path (inline trig) + V-path + trig-table path ----------------
__global__ void kv_prep(const float* __restrict__ xk, const float* __restrict__ xv,
                        float* __restrict__ ctab, float* __restrict__ stab,
                        u16* __restrict__ Kn, u16* __restrict__ Vt) {
    __shared__ u16 tile[64][66];      // used by V-path only
    int bid = blockIdx.x;
    int t = threadIdx.x;
    if (bid < 2048) {
        int bh = bid >> 6, stile = bid & 63;
        int b = bh >> 4, h = bh & 15;
        int lr = t >> 2, a = t & 3;
        int s = stile * 64 + lr;
        float c8[8], s8[8];
#pragma unroll
        for (int i = 0; i < 8; ++i) {
            float invf = exp2f((float)(8 * a + i) * -0.4152410118f);
            float ang = (float)s * invf;
            c8[i] = cosf(ang);
            s8[i] = sinf(ang);
        }
        size_t inoff = ((size_t)(b * SEQ + s)) * DIM + h * HD;
        size_t outoff = ((size_t)bh * SEQ + s) * HD;
        norm_rope_row2(xk + inoff, c8, s8, 1.0f, Kn + outoff, a);
    } else if (bid < 4096) {
        int vb = bid - 2048;
        int bh = vb >> 6, stile = vb & 63;
        int b = bh >> 4, h = bh & 15;
        int lr = t >> 2, a = t & 3;
        int s = stile * 64 + lr;
        const float* vrow = xv + ((size_t)(b * SEQ + s)) * DIM + h * HD + 16 * a;
#pragma unroll
        for (int c = 0; c < 4; ++c) {
            float4 w = *(const float4*)(vrow + 4 * c);
            tile[lr][16 * a + 4 * c + 0] = f2bf(w.x);
            tile[lr][16 * a + 4 * c + 1] = f2bf(w.y);
            tile[lr][16 * a + 4 * c + 2] = f2bf(w.z);
            tile[lr][16 * a + 4 * c + 3] = f2bf(w.w);
        }
        __syncthreads();
        int d = t >> 2;
        u32 pk[8];
#pragma unroll
        for (int i = 0; i < 8; ++i) {
            u16 lo = tile[16 * a + 2 * i][d];
            u16 hi = tile[16 * a + 2 * i + 1][d];
            pk[i] = (u32)lo | ((u32)hi << 16);
        }
        u16* dst = Vt + ((size_t)bh * HD + d) * SEQ + stile * 64 + 16 * a;
        *(uint4*)(dst) = make_uint4(pk[0], pk[1], pk[2], pk[3]);
        *(uint4*)(dst + 8) = make_uint4(pk[4], pk[5], pk[6], pk[7]);
    } else {
        int idx = (bid - 4096) * 256 + t;   // 4096*32
        int s = idx >> 5, j = idx & 31;
        float invf = exp2f((float)j * -0.4152410118f);
        float ang = (float)s * invf;
        ctab[idx] = cosf(ang);
        stab[idx] = sinf(ang);
    }
}

// ---------------- attention: 64 q-rows/wave (two 32-col groups share one K/V fragment load)
//                  -> LDS read traffic per q-row HALVED (kernel is LDS-BW-bound: 40KB/block-tile
//                  x 20480 tiles matched the observed 1500 cyc/step at 128B/cyc). ----------------
// grid = 32 bh * 16 q-tiles(256 rows) = 512 blocks; 4 waves/block, each wave 64 q-rows.
// launch_bounds (256,2): unified cap 256 >> ~170 used — zero spill risk (r5/6/11/20 lesson).
#define KROW 72   // u16 stride per K row (144B)
#define VROW 40   // u16 stride per V row (80B)
__global__ __launch_bounds__(256, 2) void attn_kernel(const float* __restrict__ xq,
                                                      const u16* __restrict__ Kn,
                                                      const u16* __restrict__ Vt,
                                                      const float* __restrict__ ctab,
                                                      const float* __restrict__ stab,
                                                      float* __restrict__ out) {
    __shared__ __align__(16) u16 Kl[2][32 * KROW];   //  9216 B
    __shared__ __align__(16) u16 Vl[2][64 * VROW];   // 10240 B
    int phys = blockIdx.x;
    int logical = (phys & 7) * 64 + (phys >> 3);    // bijective: 512 = 8 * 64
    int bh = logical >> 4, qt = logical & 15;
    int b = bh >> 4, h = bh & 15;
    int tid = threadIdx.x;
    int w = tid >> 6, l = tid & 63;
    int q = l & 31, hi = l >> 5;
    int qblk = qt * 256;
    int qw0 = qblk + w * 64;
    const u16* Kh = Kn + (size_t)bh * SEQ * HD;
    const u16* Vh = Vt + (size_t)bh * HD * SEQ;
    int dqA = qw0 + q;
    int dqB = dqA + 32;

    int bt0 = (qblk - (WIN - 1)) >> 5; if (bt0 < 0) bt0 = 0;
    int bt1 = (qblk + 224) >> 5;

    // staging assignments (per thread, constant across tiles)
    int krow = tid >> 3, kc = (tid & 7) * 8;        // K: 32 rows x 8 chunks of 8 u16
    int vrw  = tid >> 2, vc = (tid & 3) * 8;        // V: 64 rows x 4 chunks of 8 u16
    const u16* kgl = Kh + (size_t)krow * HD + kc;
    const u16* vgl = Vh + (size_t)vrw * SEQ + vc;
    u16* kls0 = &Kl[0][krow * KROW + kc];
    u16* kls1 = &Kl[1][krow * KROW + kc];
    u16* vls0 = &Vl[0][vrw * VROW + vc];
    u16* vls1 = &Vl[1][vrw * VROW + vc];

    // ---- prologue part 1: stage tile bt0 into buffer 0 FIRST ----
    {
        uint4 gk = *(const uint4*)(kgl + ((size_t)bt0 << 5) * HD);
        uint4 gv = *(const uint4*)(vgl + (bt0 << 5));
        *(uint4*)kls0 = gk;
        *(uint4*)vls0 = gv;
    }

    // ---- prologue part 2: fused Q prep for both row groups (sequential, low reg pressure) ----
    auto makeQ = [&](int dq, bf16x8& f0, bf16x8& f1, bf16x8& f2, bf16x8& f3) {
        const float* qrow = xq + ((size_t)(b * SEQ + dq)) * DIM + h * HD;
        float4 xa0 = *(const float4*)(qrow + hi * 8);
        float4 xa1 = *(const float4*)(qrow + hi * 8 + 4);
        float4 xb0 = *(const float4*)(qrow + 16 + hi * 8);
        float4 xb1 = *(const float4*)(qrow + 16 + hi * 8 + 4);
        float4 ya0 = *(const float4*)(qrow + 32 + hi * 8);
        float4 ya1 = *(const float4*)(qrow + 36 + hi * 8);
        float4 yb0 = *(const float4*)(qrow + 48 + hi * 8);
        float4 yb1 = *(const float4*)(qrow + 52 + hi * 8);
        auto d4 = [](float4 v) { return v.x * v.x + v.y * v.y + v.z * v.z + v.w * v.w; };
        float ss = d4(xa0) + d4(xa1) + d4(xb0) + d4(xb1) + d4(ya0) + d4(ya1) + d4(yb0) + d4(yb1);
        ss += __shfl_xor(ss, 32);
        float rn = (0.125f * 1.44269504f) / fmaxf(sqrtf(ss), 1e-6f);
        const float* crp = ctab + (size_t)dq * 32;
        const float* srp = stab + (size_t)dq * 32;
        float4 ca0 = *(const float4*)(crp + hi * 8);
        float4 ca1 = *(const float4*)(crp + hi * 8 + 4);
        float4 cb0 = *(const float4*)(crp + 16 + hi * 8);
        float4 cb1 = *(const float4*)(crp + 16 + hi * 8 + 4);
        float4 sa0 = *(const float4*)(srp + hi * 8);
        float4 sa1 = *(const float4*)(srp + hi * 8 + 4);
        float4 sb0 = *(const float4*)(srp + 16 + hi * 8);
        float4 sb1 = *(const float4*)(srp + 16 + hi * 8 + 4);
        u32x4 r;
        r[0] = cvtpk((xa0.x * ca0.x + ya0.x * sa0.x) * rn, (xa0.y * ca0.y + ya0.y * sa0.y) * rn);
        r[1] = cvtpk((xa0.z * ca0.z + ya0.z * sa0.z) * rn, (xa0.w * ca0.w + ya0.w * sa0.w) * rn);
        r[2] = cvtpk((xa1.x * ca1.x + ya1.x * sa1.x) * rn, (xa1.y * ca1.y + ya1.y * sa1.y) * rn);
        r[3] = cvtpk((xa1.z * ca1.z + ya1.z * sa1.z) * rn, (xa1.w * ca1.w + ya1.w * sa1.w) * rn);
        f0 = __builtin_bit_cast(bf16x8, r);
        r[0] = cvtpk((xb0.x * cb0.x + yb0.x * sb0.x) * rn, (xb0.y * cb0.y + yb0.y * sb0.y) * rn);
        r[1] = cvtpk((xb0.z * cb0.z + yb0.z * sb0.z) * rn, (xb0.w * cb0.w + yb0.w * sb0.w) * rn);
        r[2] = cvtpk((xb1.x * cb1.x + yb1.x * sb1.x) * rn, (xb1.y * cb1.y + yb1.y * sb1.y) * rn);
        r[3] = cvtpk((xb1.z * cb1.z + yb1.z * sb1.z) * rn, (xb1.w * cb1.w + yb1.w * sb1.w) * rn);
        f1 = __builtin_bit_cast(bf16x8, r);
        r[0] = cvtpk((ya0.x * ca0.x - xa0.x * sa0.x) * rn, (ya0.y * ca0.y - xa0.y * sa0.y) * rn);
        r[1] = cvtpk((ya0.z * ca0.z - xa0.z * sa0.z) * rn, (ya0.w * ca0.w - xa0.w * sa0.w) * rn);
        r[2] = cvtpk((ya1.x * ca1.x - xa1.x * sa1.x) * rn, (ya1.y * ca1.y - xa1.y * sa1.y) * rn);
        r[3] = cvtpk((ya1.z * ca1.z - xa1.z * sa1.z) * rn, (ya1.w * ca1.w - xa1.w * sa1.w) * rn);
        f2 = __builtin_bit_cast(bf16x8, r);
        r[0] = cvtpk((yb0.x * cb0.x - xb0.x * sb0.x) * rn, (yb0.y * cb0.y - xb0.y * sb0.y) * rn);
        r[1] = cvtpk((yb0.z * cb0.z - xb0.z * sb0.z) * rn, (yb0.w * cb0.w - xb0.w * sb0.w) * rn);
        r[2] = cvtpk((yb1.x * cb1.x - xb1.x * sb1.x) * rn, (yb1.y * cb1.y - xb1.y * sb1.y) * rn);
        r[3] = cvtpk((yb1.z * cb1.z - xb1.z * sb1.z) * rn, (yb1.w * cb1.w - xb1.w * sb1.w) * rn);
        f3 = __builtin_bit_cast(bf16x8, r);
    };
    bf16x8 qfA0, qfA1, qfA2, qfA3, qfB0, qfB1, qfB2, qfB3;
    makeQ(dqA, qfA0, qfA1, qfA2, qfA3);
    makeQ(dqB, qfB0, qfB1, qfB2, qfB3);

    f32x16 accA0, accA1, accB0, accB1;
#pragma unroll
    for (int i = 0; i < 16; ++i) { accA0[i] = 0.f; accA1[i] = 0.f; accB0[i] = 0.f; accB1[i] = 0.f; }
    float lA = 0.f, lB = 0.f;

    int twA0 = (qw0 - (WIN - 1)) >> 5; if (twA0 < 0) twA0 = 0;
    int twA1 = qw0 >> 5;
    int twB0 = (qw0 + 32 - (WIN - 1)) >> 5; if (twB0 < 0) twB0 = 0;
    int twB1 = (qw0 + 32) >> 5;

    // compute-phase LDS read bases
    const u16* krd0 = &Kl[0][q * KROW + hi * 8];
    const u16* krd1 = &Kl[1][q * KROW + hi * 8];
    const u16* vrd0a = &Vl[0][q * VROW + hi * 8];
    const u16* vrd0b = &Vl[0][(32 + q) * VROW + hi * 8];
    const u16* vrd1a = &Vl[1][q * VROW + hi * 8];
    const u16* vrd1b = &Vl[1][(32 + q) * VROW + hi * 8];

    __syncthreads();   // buf0 ready

    int c = 0;
    for (int t = bt0; t <= bt1; ++t) {
        int kv0 = t << 5;
        bool more = t < bt1;       // block-uniform
        uint4 gk, gv;
        if (more) {
            gk = *(const uint4*)(kgl + ((size_t)(kv0 + 32)) * HD);
            gv = *(const uint4*)(vgl + (kv0 + 32));
        }
        __builtin_amdgcn_sched_barrier(0);   // pin load issue before compute

        bool inA = (t >= twA0) && (t <= twA1);
        bool inB = (t >= twB0) && (t <= twB1);
        if (inA || inB) {
            const u16* kr = c ? krd1 : krd0;
            bf16x8 k0 = *(const bf16x8*)(kr);
            bf16x8 k1 = *(const bf16x8*)(kr + 16);
            bf16x8 k2 = *(const bf16x8*)(kr + 32);
            bf16x8 k3 = *(const bf16x8*)(kr + 48);

            f32x16 stA, stB;
            __builtin_amdgcn_s_setprio(1);
            if (inA) {
#pragma unroll
                for (int i = 0; i < 16; ++i) stA[i] = 0.f;
                stA = __builtin_amdgcn_mfma_f32_32x32x16_bf16(k0, qfA0, stA, 0, 0, 0);
                stA = __builtin_amdgcn_mfma_f32_32x32x16_bf16(k1, qfA1, stA, 0, 0, 0);
                stA = __builtin_amdgcn_mfma_f32_32x32x16_bf16(k2, qfA2, stA, 0, 0, 0);
                stA = __builtin_amdgcn_mfma_f32_32x32x16_bf16(k3, qfA3, stA, 0, 0, 0);
            }
            if (inB) {
#pragma unroll
                for (int i = 0; i < 16; ++i) stB[i] = 0.f;
                stB = __builtin_amdgcn_mfma_f32_32x32x16_bf16(k0, qfB0, stB, 0, 0, 0);
                stB = __builtin_amdgcn_mfma_f32_32x32x16_bf16(k1, qfB1, stB, 0, 0, 0);
                stB = __builtin_amdgcn_mfma_f32_32x32x16_bf16(k2, qfB2, stB, 0, 0, 0);
                stB = __builtin_amdgcn_mfma_f32_32x32x16_bf16(k3, qfB3, stB, 0, 0, 0);
            }
            __builtin_amdgcn_s_setprio(0);

            const u16* va = c ? vrd1a : vrd0a;
            const u16* vb = c ? vrd1b : vrd0b;
            bf16x8 va0 = *(const bf16x8*)(va);
            bf16x8 va1 = *(const bf16x8*)(va + 16);
            bf16x8 vb0 = *(const bf16x8*)(vb);
            bf16x8 vb1 = *(const bf16x8*)(vb + 16);

            auto smpv = [&](const f32x16& st, int dq, bool mask,
                            f32x16& a0, f32x16& a1, float& lsum) {
                int base = dq - (kv0 + 4 * hi);
                u32 wd[8];
                float l0 = 0.f, l1 = 0.f;
#pragma unroll
                for (int i = 0; i < 8; ++i) {
                    int r0 = 2 * i, r1 = 2 * i + 1;
                    float e0 = pexp2(st[r0]);
                    float e1 = pexp2(st[r1]);
                    if (mask) {
                        int k0off = (r0 & 3) + 8 * (r0 >> 2);
                        int k1off = (r1 & 3) + 8 * (r1 >> 2);
                        e0 = ((u32)(base - k0off) < (u32)WIN) ? e0 : 0.f;
                        e1 = ((u32)(base - k1off) < (u32)WIN) ? e1 : 0.f;
                    }
                    l0 += e0; l1 += e1;
                    wd[i] = cvtpk(e0, e1);
                }
                lsum += l0 + l1;
                u32x4 b1, b2;
#if __has_builtin(__builtin_amdgcn_permlane32_swap)
                u32x2 sA = __builtin_amdgcn_permlane32_swap(wd[0], wd[2], false, false);
                u32x2 sB = __builtin_amdgcn_permlane32_swap(wd[1], wd[3], false, false);
                u32x2 sC = __builtin_amdgcn_permlane32_swap(wd[4], wd[6], false, false);
                u32x2 sD = __builtin_amdgcn_permlane32_swap(wd[5], wd[7], false, false);
                b1 = (u32x4){ sA[0], sB[0], sA[1], sB[1] };
                b2 = (u32x4){ sC[0], sD[0], sC[1], sD[1] };
#else
                u32 e0 = __shfl_xor(hi ? wd[0] : wd[2], 32);
                u32 e1 = __shfl_xor(hi ? wd[1] : wd[3], 32);
                u32 e2 = __shfl_xor(hi ? wd[4] : wd[6], 32);
                u32 e3 = __shfl_xor(hi ? wd[5] : wd[7], 32);
                b1 = (u32x4){ hi ? e0 : wd[0], hi ? e1 : wd[1], hi ? wd[2] : e0, hi ? wd[3] : e1 };
                b2 = (u32x4){ hi ? e2 : wd[4], hi ? e3 : wd[5], hi ? wd[6] : e2, hi ? wd[7] : e3 };
#endif
                bf16x8 pb1 = __builtin_bit_cast(bf16x8, b1);
                bf16x8 pb2 = __builtin_bit_cast(bf16x8, b2);
                __builtin_amdgcn_s_setprio(1);
                a0 = __builtin_amdgcn_mfma_f32_32x32x16_bf16(va0, pb1, a0, 0, 0, 0);
                a0 = __builtin_amdgcn_mfma_f32_32x32x16_bf16(va1, pb2, a0, 0, 0, 0);
                a1 = __builtin_amdgcn_mfma_f32_32x32x16_bf16(vb0, pb1, a1, 0, 0, 0);
                a1 = __builtin_amdgcn_mfma_f32_32x32x16_bf16(vb1, pb2, a1, 0, 0, 0);
                __builtin_amdgcn_s_setprio(0);
            };

            if (inA) smpv(stA, dqA, (t == twA0) || (t == twA1), accA0, accA1, lA);
            if (inB) smpv(stB, dqB, (t == twB0) || (t == twB1), accB0, accB1, lB);
        }

        if (more) {
            *(uint4*)(c ? kls0 : kls1) = gk;
            *(uint4*)(c ? vls0 : vls1) = gv;
            __syncthreads();
        }
        c ^= 1;
    }

    lA += __shfl_xor(lA, 32);
    lB += __shfl_xor(lB, 32);
    float invA = 1.0f / lA;
    float invB = 1.0f / lB;
    float* orowA = out + ((size_t)(b * SEQ + dqA)) * DIM + h * HD;
    float* orowB = out + ((size_t)(b * SEQ + dqB)) * DIM + h * HD;
#pragma unroll
    for (int g = 0; g < 4; ++g) {
        float4 v0 = { accA0[4 * g + 0] * invA, accA0[4 * g + 1] * invA,
                      accA0[4 * g + 2] * invA, accA0[4 * g + 3] * invA };
        float4 v1 = { accA1[4 * g + 0] * invA, accA1[4 * g + 1] * invA,
                      accA1[4 * g + 2] * invA, accA1[4 * g + 3] * invA };
        *(float4*)(orowA + 8 * g + 4 * hi) = v0;
        *(float4*)(orowA + 32 + 8 * g + 4 * hi) = v1;
        float4 w0 = { accB0[4 * g + 0] * invB, accB0[4 * g + 1] * invB,
                      accB0[4 * g + 2] * invB, accB0[4 * g + 3] * invB };
        float4 w1 = { accB1[4 * g + 0] * invB, accB1[4 * g + 1] * invB,
                      accB1[4 * g + 2] * invB, accB1[4 * g + 3] * invB };
        *(float4*)(orowB + 8 * g + 4 * hi) = w0;
        *(float4*)(orowB + 32 + 8 * g + 4 * hi) = w1;
    }
}

extern "C" void kernel_launch(void* const* d_in, const int* in_sizes, int n_in,
                              void* d_out, int out_size, void* d_ws, size_t ws_size,
                              hipStream_t stream) {
    (void)in_sizes; (void)n_in; (void)out_size; (void)ws_size;
    const float* xq = (const float*)d_in[0];
    const float* xk = (const float*)d_in[1];
    const float* xv = (const float*)d_in[2];
    float* out = (float*)d_out;

    const size_t HEADS_ELEMS = (size_t)NB * NH * SEQ * HD;   // 8,388,608
    u16* Kn = (u16*)d_ws;
    u16* Vt = Kn + HEADS_ELEMS;
    float* ctab = (float*)(Vt + HEADS_ELEMS);
    float* stab = ctab + (size_t)SEQ * 32;

    kv_prep<<<dim3(4608), dim3(256), 0, stream>>>(xk, xv, ctab, stab, Kn, Vt);
    attn_kernel<<<dim3(512), dim3(256), 0, stream>>>(xq, Kn, Vt, ctab, stab, out);
}

// Round 23
// 61.039 us; speedup vs baseline: 1.1708x; 1.1708x over previous
//
#include <hip/hip_runtime.h>

#define NB 2
#define NH 16
#define SEQ 4096
#define HD 64
#define DIM 1024
#define WIN 512

typedef float f32x16 __attribute__((ext_vector_type(16)));
typedef short bf16x8 __attribute__((ext_vector_type(8)));
typedef unsigned int u32x4 __attribute__((ext_vector_type(4)));
typedef unsigned int u32x2 __attribute__((ext_vector_type(2)));
typedef unsigned short u16;
typedef unsigned int u32;

__device__ __forceinline__ u16 f2bf(float x) {
    u32 u = __float_as_uint(x);
    u += 0x7FFFu + ((u >> 16) & 1u);
    return (u16)(u >> 16);
}

// pack 2 f32 -> 1 u32 of 2 bf16 (RNE) in one VALU op
__device__ __forceinline__ u32 cvtpk(float lo, float hi) {
    u32 r;
    asm("v_cvt_pk_bf16_f32 %0, %1, %2" : "=v"(r) : "v"(lo), "v"(hi));
    return r;
}

// quadratic 2^x for |x| <= 0.19 (l2-norm bounds scores): rel err < 3.5e-4 (<< bf16 4e-3)
__device__ __forceinline__ float pexp2(float x) {
    return 1.f + x * (0.69314718f + x * 0.24022651f);
}

// ---------------- k: l2-normalize + rope -> bf16, head-major (local trig arrays) ----------------
__device__ __forceinline__ void norm_rope_row2(const float* __restrict__ row,
                                               const float (&cr)[8], const float (&sr)[8],
                                               float scale, u16* __restrict__ dst, int a) {
    float4 u0 = *(const float4*)(row + 8 * a);
    float4 u1 = *(const float4*)(row + 8 * a + 4);
    float4 v0 = *(const float4*)(row + 32 + 8 * a);
    float4 v1 = *(const float4*)(row + 32 + 8 * a + 4);
    float x1[8] = {u0.x, u0.y, u0.z, u0.w, u1.x, u1.y, u1.z, u1.w};
    float x2[8] = {v0.x, v0.y, v0.z, v0.w, v1.x, v1.y, v1.z, v1.w};
    float ss = 0.f;
#pragma unroll
    for (int i = 0; i < 8; ++i) ss += x1[i] * x1[i] + x2[i] * x2[i];
    ss += __shfl_xor(ss, 1);
    ss += __shfl_xor(ss, 2);
    float rn = scale / fmaxf(sqrtf(ss), 1e-6f);
    u16 o1[8], o2[8];
#pragma unroll
    for (int i = 0; i < 8; ++i) {
        float c = cr[i], sn = sr[i];
        o1[i] = f2bf((x1[i] * c + x2[i] * sn) * rn);
        o2[i] = f2bf((x2[i] * c - x1[i] * sn) * rn);
    }
    uint4 w1, w2;
    w1.x = (u32)o1[0] | ((u32)o1[1] << 16); w1.y = (u32)o1[2] | ((u32)o1[3] << 16);
    w1.z = (u32)o1[4] | ((u32)o1[5] << 16); w1.w = (u32)o1[6] | ((u32)o1[7] << 16);
    w2.x = (u32)o2[0] | ((u32)o2[1] << 16); w2.y = (u32)o2[2] | ((u32)o2[3] << 16);
    w2.z = (u32)o2[4] | ((u32)o2[5] << 16); w2.w = (u32)o2[6] | ((u32)o2[7] << 16);
    *(uint4*)(dst + 8 * a) = w1;
    *(uint4*)(dst + 32 + 8 * a) = w2;
}

// ---------------- merged prep: K-path (inline trig) + V-path + trig-table path ----------------
// grid 4608: [0,2048) K, [2048,4096) V, [4096,4608) trig table (consumed only by attn)
__global__ void kv_prep(const float* __restrict__ xk, const float* __restrict__ xv,
                        float* __restrict__ ctab, float* __restrict__ stab,
                        u16* __restrict__ Kn, u16* __restrict__ Vt) {
    __shared__ u16 tile[64][66];      // used by V-path only
    int bid = blockIdx.x;
    int t = threadIdx.x;
    if (bid < 2048) {
        // ---- K path: l2-normalize + rope -> bf16 head-major; trig computed inline ----
        int bh = bid >> 6, stile = bid & 63;
        int b = bh >> 4, h = bh & 15;
        int lr = t >> 2, a = t & 3;
        int s = stile * 64 + lr;
        float c8[8], s8[8];
#pragma unroll
        for (int i = 0; i < 8; ++i) {
            // invf = theta^(-j/32) = exp2(j * log2(1e-4)/32)
            float invf = exp2f((float)(8 * a + i) * -0.4152410118f);
            float ang = (float)s * invf;
            c8[i] = cosf(ang);
            s8[i] = sinf(ang);
        }
        size_t inoff = ((size_t)(b * SEQ + s)) * DIM + h * HD;
        size_t outoff = ((size_t)bh * SEQ + s) * HD;
        norm_rope_row2(xk + inoff, c8, s8, 1.0f, Kn + outoff, a);
    } else if (bid < 4096) {
        // ---- V path: bf16 + transpose to Vt[bh][dim][s] ----
        int vb = bid - 2048;
        int bh = vb >> 6, stile = vb & 63;
        int b = bh >> 4, h = bh & 15;
        int lr = t >> 2, a = t & 3;
        int s = stile * 64 + lr;
        const float* vrow = xv + ((size_t)(b * SEQ + s)) * DIM + h * HD + 16 * a;
#pragma unroll
        for (int c = 0; c < 4; ++c) {
            float4 w = *(const float4*)(vrow + 4 * c);
            tile[lr][16 * a + 4 * c + 0] = f2bf(w.x);
            tile[lr][16 * a + 4 * c + 1] = f2bf(w.y);
            tile[lr][16 * a + 4 * c + 2] = f2bf(w.z);
            tile[lr][16 * a + 4 * c + 3] = f2bf(w.w);
        }
        __syncthreads();
        int d = t >> 2;
        u32 pk[8];
#pragma unroll
        for (int i = 0; i < 8; ++i) {
            u16 lo = tile[16 * a + 2 * i][d];
            u16 hi = tile[16 * a + 2 * i + 1][d];
            pk[i] = (u32)lo | ((u32)hi << 16);
        }
        u16* dst = Vt + ((size_t)bh * HD + d) * SEQ + stile * 64 + 16 * a;
        *(uint4*)(dst) = make_uint4(pk[0], pk[1], pk[2], pk[3]);
        *(uint4*)(dst + 8) = make_uint4(pk[4], pk[5], pk[6], pk[7]);
    } else {
        // ---- trig-table path (for attn's fused Q-prep; attn launches after kv_prep) ----
        int idx = (bid - 4096) * 256 + t;   // 4096*32
        int s = idx >> 5, j = idx & 31;
        float invf = exp2f((float)j * -0.4152410118f);
        float ang = (float)s * invf;
        ctab[idx] = cosf(ang);
        stab[idx] = sinf(ang);
    }
}

// ---------------- attention: r19 structure verbatim, launch_bounds (256,4) — the ONLY
//                  register budget that fits (~108 unified used; 102-cap spilled in r20) ----------------
// grid = 32 bh * 32 q-tiles(128 rows) = 1024 blocks; 4 waves/block, each wave 32 q-rows.
#define KROW 72   // u16 stride per K row (144B)
#define VROW 40   // u16 stride per V row (80B)
__global__ __launch_bounds__(256, 4) void attn_kernel(const float* __restrict__ xq,
                                                      const u16* __restrict__ Kn,
                                                      const u16* __restrict__ Vt,
                                                      const float* __restrict__ ctab,
                                                      const float* __restrict__ stab,
                                                      float* __restrict__ out) {
    __shared__ __align__(16) u16 Kl[2][32 * KROW];   //  9216 B
    __shared__ __align__(16) u16 Vl[2][64 * VROW];   // 10240 B
    int phys = blockIdx.x;
    int logical = (phys & 7) * 128 + (phys >> 3);   // bijective: 1024 = 8 * 128
    int bh = logical >> 5, qt = logical & 31;
    int b = bh >> 4, h = bh & 15;
    int tid = threadIdx.x;
    int w = tid >> 6, l = tid & 63;
    int q = l & 31, hi = l >> 5;
    int qblk = qt * 128;
    int qw0 = qblk + w * 32;
    const u16* Kh = Kn + (size_t)bh * SEQ * HD;
    const u16* Vh = Vt + (size_t)bh * HD * SEQ;
    int dq = qw0 + q;

    int bt0 = (qblk - (WIN - 1)) >> 5; if (bt0 < 0) bt0 = 0;
    int bt1 = (qblk + 96) >> 5;

    // staging assignments (per thread, constant across tiles)
    int krow = tid >> 3, kc = (tid & 7) * 8;        // K: 32 rows x 8 chunks of 8 u16
    int vrw  = tid >> 2, vc = (tid & 3) * 8;        // V: 64 rows x 4 chunks of 8 u16
    const u16* kgl = Kh + (size_t)krow * HD + kc;   // + kv0*HD per tile
    const u16* vgl = Vh + (size_t)vrw * SEQ + vc;   // + kv0 per tile
    u16* kls0 = &Kl[0][krow * KROW + kc];
    u16* kls1 = &Kl[1][krow * KROW + kc];
    u16* vls0 = &Vl[0][vrw * VROW + vc];
    u16* vls1 = &Vl[1][vrw * VROW + vc];

    // ---- prologue part 1: issue tile-bt0 staging loads + write to LDS buf0 FIRST ----
    {
        uint4 gk = *(const uint4*)(kgl + ((size_t)bt0 << 5) * HD);
        uint4 gv = *(const uint4*)(vgl + (bt0 << 5));
        *(uint4*)kls0 = gk;
        *(uint4*)vls0 = gv;
    }

    // ---- prologue part 2: fused Q prep (loads overlap the staging waits) ----
    const float* qrow = xq + ((size_t)(b * SEQ + dq)) * DIM + h * HD;
    float4 xa0 = *(const float4*)(qrow + hi * 8);
    float4 xa1 = *(const float4*)(qrow + hi * 8 + 4);
    float4 xb0 = *(const float4*)(qrow + 16 + hi * 8);
    float4 xb1 = *(const float4*)(qrow + 16 + hi * 8 + 4);
    float4 ya0 = *(const float4*)(qrow + 32 + hi * 8);
    float4 ya1 = *(const float4*)(qrow + 36 + hi * 8);
    float4 yb0 = *(const float4*)(qrow + 48 + hi * 8);
    float4 yb1 = *(const float4*)(qrow + 52 + hi * 8);
    auto d4 = [](float4 v) { return v.x * v.x + v.y * v.y + v.z * v.z + v.w * v.w; };
    float ss = d4(xa0) + d4(xa1) + d4(xb0) + d4(xb1) + d4(ya0) + d4(ya1) + d4(yb0) + d4(yb1);
    ss += __shfl_xor(ss, 32);
    float rn = (0.125f * 1.44269504f) / fmaxf(sqrtf(ss), 1e-6f);
    const float* crp = ctab + (size_t)dq * 32;
    const float* srp = stab + (size_t)dq * 32;
    float4 ca0 = *(const float4*)(crp + hi * 8);
    float4 ca1 = *(const float4*)(crp + hi * 8 + 4);
    float4 cb0 = *(const float4*)(crp + 16 + hi * 8);
    float4 cb1 = *(const float4*)(crp + 16 + hi * 8 + 4);
    float4 sa0 = *(const float4*)(srp + hi * 8);
    float4 sa1 = *(const float4*)(srp + hi * 8 + 4);
    float4 sb0 = *(const float4*)(srp + 16 + hi * 8);
    float4 sb1 = *(const float4*)(srp + 16 + hi * 8 + 4);
    auto mk1 = [&](float4 x0, float4 x1f, float4 y0, float4 y1f,
                   float4 c0, float4 c1, float4 s0, float4 s1) -> bf16x8 {
        u32x4 r;
        r[0] = cvtpk((x0.x * c0.x + y0.x * s0.x) * rn, (x0.y * c0.y + y0.y * s0.y) * rn);
        r[1] = cvtpk((x0.z * c0.z + y0.z * s0.z) * rn, (x0.w * c0.w + y0.w * s0.w) * rn);
        r[2] = cvtpk((x1f.x * c1.x + y1f.x * s1.x) * rn, (x1f.y * c1.y + y1f.y * s1.y) * rn);
        r[3] = cvtpk((x1f.z * c1.z + y1f.z * s1.z) * rn, (x1f.w * c1.w + y1f.w * s1.w) * rn);
        return __builtin_bit_cast(bf16x8, r);
    };
    auto mk2 = [&](float4 x0, float4 x1f, float4 y0, float4 y1f,
                   float4 c0, float4 c1, float4 s0, float4 s1) -> bf16x8 {
        u32x4 r;
        r[0] = cvtpk((y0.x * c0.x - x0.x * s0.x) * rn, (y0.y * c0.y - x0.y * s0.y) * rn);
        r[1] = cvtpk((y0.z * c0.z - x0.z * s0.z) * rn, (y0.w * c0.w - x0.w * s0.w) * rn);
        r[2] = cvtpk((y1f.x * c1.x - x1f.x * s1.x) * rn, (y1f.y * c1.y - x1f.y * s1.y) * rn);
        r[3] = cvtpk((y1f.z * c1.z - x1f.z * s1.z) * rn, (y1f.w * c1.w - x1f.w * s1.w) * rn);
        return __builtin_bit_cast(bf16x8, r);
    };
    bf16x8 qf0 = mk1(xa0, xa1, ya0, ya1, ca0, ca1, sa0, sa1);
    bf16x8 qf1 = mk1(xb0, xb1, yb0, yb1, cb0, cb1, sb0, sb1);
    bf16x8 qf2 = mk2(xa0, xa1, ya0, ya1, ca0, ca1, sa0, sa1);
    bf16x8 qf3 = mk2(xb0, xb1, yb0, yb1, cb0, cb1, sb0, sb1);

    f32x16 acc0, acc1;
#pragma unroll
    for (int i = 0; i < 16; ++i) { acc0[i] = 0.f; acc1[i] = 0.f; }
    float l_ = 0.f;

    int tw0 = (qw0 - (WIN - 1)) >> 5; if (tw0 < 0) tw0 = 0;
    int tw1 = qw0 >> 5;

    // compute-phase LDS read bases
    const u16* krd0 = &Kl[0][q * KROW + hi * 8];
    const u16* krd1 = &Kl[1][q * KROW + hi * 8];
    const u16* vrd0a = &Vl[0][q * VROW + hi * 8];
    const u16* vrd0b = &Vl[0][(32 + q) * VROW + hi * 8];
    const u16* vrd1a = &Vl[1][q * VROW + hi * 8];
    const u16* vrd1b = &Vl[1][(32 + q) * VROW + hi * 8];

    __syncthreads();   // buf0 ready

    int c = 0;
    for (int t = bt0; t <= bt1; ++t) {
        int kv0 = t << 5;
        bool more = t < bt1;       // block-uniform
        uint4 gk, gv;
        if (more) {   // issue next-tile global loads BEFORE compute (latency hides under it)
            gk = *(const uint4*)(kgl + ((size_t)(kv0 + 32)) * HD);
            gv = *(const uint4*)(vgl + (kv0 + 32));
        }
        // pin the load issue here (prevents sinking to the ds_write use point)
        __builtin_amdgcn_sched_barrier(0);

        if (t >= tw0 && t <= tw1) {
            bool mask = (t == tw0) || (t == tw1);
            const u16* kr = c ? krd1 : krd0;
            const u16* va = c ? vrd1a : vrd0a;
            const u16* vb = c ? vrd1b : vrd0b;

            bf16x8 k0 = *(const bf16x8*)(kr);
            bf16x8 k1 = *(const bf16x8*)(kr + 16);
            bf16x8 k2 = *(const bf16x8*)(kr + 32);
            bf16x8 k3 = *(const bf16x8*)(kr + 48);

            f32x16 st;
#pragma unroll
            for (int i = 0; i < 16; ++i) st[i] = 0.f;
            __builtin_amdgcn_s_setprio(1);
            st = __builtin_amdgcn_mfma_f32_32x32x16_bf16(k0, qf0, st, 0, 0, 0);
            st = __builtin_amdgcn_mfma_f32_32x32x16_bf16(k1, qf1, st, 0, 0, 0);
            st = __builtin_amdgcn_mfma_f32_32x32x16_bf16(k2, qf2, st, 0, 0, 0);
            st = __builtin_amdgcn_mfma_f32_32x32x16_bf16(k3, qf3, st, 0, 0, 0);
            __builtin_amdgcn_s_setprio(0);

            bf16x8 va0 = *(const bf16x8*)(va);
            bf16x8 va1 = *(const bf16x8*)(va + 16);
            bf16x8 vb0 = *(const bf16x8*)(vb);
            bf16x8 vb1 = *(const bf16x8*)(vb + 16);

            // fused softmax: quadratic exp2 on main VALU pipe, fixed shift (|S| <= 0.19)
            int base = dq - (kv0 + 4 * hi);
            u32 wd[8];
            float l0 = 0.f, l1 = 0.f;
#pragma unroll
            for (int i = 0; i < 8; ++i) {
                int r0 = 2 * i, r1 = 2 * i + 1;
                float e0 = pexp2(st[r0]);
                float e1 = pexp2(st[r1]);
                if (mask) {
                    int k0off = (r0 & 3) + 8 * (r0 >> 2);
                    int k1off = (r1 & 3) + 8 * (r1 >> 2);
                    e0 = ((u32)(base - k0off) < (u32)WIN) ? e0 : 0.f;
                    e1 = ((u32)(base - k1off) < (u32)WIN) ? e1 : 0.f;
                }
                l0 += e0; l1 += e1;
                wd[i] = cvtpk(e0, e1);
            }
            l_ += l0 + l1;

            // P^T B-fragment via permlane32_swap (T12)
            u32x4 b1, b2;
#if __has_builtin(__builtin_amdgcn_permlane32_swap)
            u32x2 sA = __builtin_amdgcn_permlane32_swap(wd[0], wd[2], false, false);
            u32x2 sB = __builtin_amdgcn_permlane32_swap(wd[1], wd[3], false, false);
            u32x2 sC = __builtin_amdgcn_permlane32_swap(wd[4], wd[6], false, false);
            u32x2 sD = __builtin_amdgcn_permlane32_swap(wd[5], wd[7], false, false);
            b1 = (u32x4){ sA[0], sB[0], sA[1], sB[1] };
            b2 = (u32x4){ sC[0], sD[0], sC[1], sD[1] };
#else
            u32 e0 = __shfl_xor(hi ? wd[0] : wd[2], 32);
            u32 e1 = __shfl_xor(hi ? wd[1] : wd[3], 32);
            u32 e2 = __shfl_xor(hi ? wd[4] : wd[6], 32);
            u32 e3 = __shfl_xor(hi ? wd[5] : wd[7], 32);
            b1 = (u32x4){ hi ? e0 : wd[0], hi ? e1 : wd[1], hi ? wd[2] : e0, hi ? wd[3] : e1 };
            b2 = (u32x4){ hi ? e2 : wd[4], hi ? e3 : wd[5], hi ? wd[6] : e2, hi ? wd[7] : e3 };
#endif
            bf16x8 pb1 = __builtin_bit_cast(bf16x8, b1);
            bf16x8 pb2 = __builtin_bit_cast(bf16x8, b2);

            __builtin_amdgcn_s_setprio(1);
            acc0 = __builtin_amdgcn_mfma_f32_32x32x16_bf16(va0, pb1, acc0, 0, 0, 0);
            acc0 = __builtin_amdgcn_mfma_f32_32x32x16_bf16(va1, pb2, acc0, 0, 0, 0);
            acc1 = __builtin_amdgcn_mfma_f32_32x32x16_bf16(vb0, pb1, acc1, 0, 0, 0);
            acc1 = __builtin_amdgcn_mfma_f32_32x32x16_bf16(vb1, pb2, acc1, 0, 0, 0);
            __builtin_amdgcn_s_setprio(0);
        }

        if (more) {   // write staged tile to the other buffer, then sync (skipped on last tile)
            *(uint4*)(c ? kls0 : kls1) = gk;
            *(uint4*)(c ? vls0 : vls1) = gv;
            __syncthreads();
        }
        c ^= 1;
    }

    l_ += __shfl_xor(l_, 32);
    float inv = 1.0f / l_;
    float* orow = out + ((size_t)(b * SEQ + dq)) * DIM + h * HD;
#pragma unroll
    for (int g = 0; g < 4; ++g) {
        float4 v0 = { acc0[4 * g + 0] * inv, acc0[4 * g + 1] * inv,
                      acc0[4 * g + 2] * inv, acc0[4 * g + 3] * inv };
        float4 v1 = { acc1[4 * g + 0] * inv, acc1[4 * g + 1] * inv,
                      acc1[4 * g + 2] * inv, acc1[4 * g + 3] * inv };
        *(float4*)(orow + 8 * g + 4 * hi) = v0;          // d = 8g + 4hi + 0..3
        *(float4*)(orow + 32 + 8 * g + 4 * hi) = v1;     // d = 32 + 8g + 4hi + 0..3
    }
}

extern "C" void kernel_launch(void* const* d_in, const int* in_sizes, int n_in,
                              void* d_out, int out_size, void* d_ws, size_t ws_size,
                              hipStream_t stream) {
    (void)in_sizes; (void)n_in; (void)out_size; (void)ws_size;
    const float* xq = (const float*)d_in[0];
    const float* xk = (const float*)d_in[1];
    const float* xv = (const float*)d_in[2];
    float* out = (float*)d_out;

    const size_t HEADS_ELEMS = (size_t)NB * NH * SEQ * HD;   // 8,388,608
    u16* Kn = (u16*)d_ws;
    u16* Vt = Kn + HEADS_ELEMS;
    float* ctab = (float*)(Vt + HEADS_ELEMS);
    float* stab = ctab + (size_t)SEQ * 32;

    kv_prep<<<dim3(4608), dim3(256), 0, stream>>>(xk, xv, ctab, stab, Kn, Vt);
    attn_kernel<<<dim3(1024), dim3(256), 0, stream>>>(xq, Kn, Vt, ctab, stab, out);
}